// Round 7
// baseline (51.968 us; speedup 1.0000x reference)
//
#include <hip/hip_runtime.h>
#include <cfloat>
#include <cmath>

#define NB     4
#define NPTS   4096
#define NLAT   512
#define RPTS   16                 // i-points per thread
#define CJ     64                 // j-points per block (one per lane, 2 sets)
#define NJC    (NPTS / CJ)        // 64 j-chunks

// Full-wave rotate-by-1 via DPP (pure VALU, no LDS pipe).
__device__ __forceinline__ float dpp_ror1(float v)
{
    return __int_as_float(__builtin_amdgcn_mov_dpp(
        __float_as_int(v), 0x13C /* wave_ror:1 */, 0xF, 0xF, true));
}

// ---------------------------------------------------------------------------
// Prep: predT/targT = (-2x,-2y,-2z,|p|^2) (j-side); predR/targR = (x,y,z,|p|^2)
// (i-side). grid = NB*NPTS/256 = 64 blocks.
// ---------------------------------------------------------------------------
__global__ __launch_bounds__(256) void k_prep(
    const float* __restrict__ pred_pos, const float* __restrict__ targ_pos,
    float4* __restrict__ predT, float4* __restrict__ predR,
    float4* __restrict__ targT, float4* __restrict__ targR)
{
    const int i = blockIdx.x * 256 + threadIdx.x;
    {
        const float x = pred_pos[3*i], y = pred_pos[3*i+1], z = pred_pos[3*i+2];
        const float p2 = fmaf(z, z, fmaf(y, y, x * x));
        predT[i] = make_float4(-2.f*x, -2.f*y, -2.f*z, p2);
        predR[i] = make_float4(x, y, z, p2);
    }
    {
        const float x = targ_pos[3*i], y = targ_pos[3*i+1], z = targ_pos[3*i+2];
        const float p2 = fmaf(z, z, fmaf(y, y, x * x));
        targT[i] = make_float4(-2.f*x, -2.f*y, -2.f*z, p2);
        targR[i] = make_float4(x, y, z, p2);
    }
}

// ---------------------------------------------------------------------------
// Kernel A: systolic partial mins. grid = 3*NB*NJC = 768; block = 256.
// Each lane holds TWO j-points in registers (j1 at lane, j2 at lane^32) and
// 16 i-points. 32 steps: compute 16 chains of {2 pairs = 6 fma + 1 min3},
// then rotate both j-sets one lane via v_mov_b32_dpp wave_ror:1.
// ZERO memory operations in the loop — pure VALU.
// Mode-2 self-pair occurs ONLY at step 0 in j1, for waves with (jc-w)%4==0,
// at chain kself=(jc-w)/4 — wave-uniform fix, no per-pair compares.
// Each (mode,b,jc,i) partial written exactly once -> deterministic.
// ---------------------------------------------------------------------------
__global__ __launch_bounds__(256) void k_min_dist(
    const float4* __restrict__ predT, const float4* __restrict__ predR,
    const float4* __restrict__ targT, const float4* __restrict__ targR,
    float* __restrict__ part_mins /* [3][NB][NJC][NPTS] */)
{
    const int tid  = threadIdx.x;
    const int lane = tid & 63;
    const int w    = tid >> 6;
    const int jc   = blockIdx.x & (NJC - 1);
    const int b    = (blockIdx.x >> 6) & 3;
    const int mode = blockIdx.x >> 8;

    const float4* iR = ((mode == 1) ? targR : predR) + (size_t)b * NPTS;
    const float4* jT = ((mode == 0) ? targT : predT) + (size_t)b * NPTS + jc * CJ;

    // two register-resident j-points per lane
    const float4 ja = jT[lane];
    const float4 jb = jT[lane ^ 32];
    float j1x = ja.x, j1y = ja.y, j1z = ja.z, j1w = ja.w;
    float j2x = jb.x, j2y = jb.y, j2z = jb.z, j2w = jb.w;

    float px[RPTS], py[RPTS], pz[RPTS], p2[RPTS], acc[RPTS];
    #pragma unroll
    for (int k = 0; k < RPTS; ++k) {
        const float4 r = iR[(k << 8) + tid];
        px[k] = r.x; py[k] = r.y; pz[k] = r.z; p2[k] = r.w;
        acc[k] = FLT_MAX;
    }

    // --- step 0 (with wave-uniform self-skip for mode 2) ---
    {
        const int  d     = jc - w;
        const bool skipw = (mode == 2) && (d >= 0) && ((d & 3) == 0);
        const int  kself = d >> 2;                 // in [0,16) when skipw
        #pragma unroll
        for (int k = 0; k < RPTS; ++k) {
            float t1 = fmaf(j1x, px[k], j1w);
            t1 = fmaf(j1y, py[k], t1);
            t1 = fmaf(j1z, pz[k], t1);
            t1 = (skipw && k == kself) ? FLT_MAX : t1;
            float t2 = fmaf(j2x, px[k], j2w);
            t2 = fmaf(j2y, py[k], t2);
            t2 = fmaf(j2z, pz[k], t2);
            acc[k] = fminf(acc[k], fminf(t1, t2));
        }
        j1x = dpp_ror1(j1x); j1y = dpp_ror1(j1y);
        j1z = dpp_ror1(j1z); j1w = dpp_ror1(j1w);
        j2x = dpp_ror1(j2x); j2y = dpp_ror1(j2y);
        j2z = dpp_ror1(j2z); j2w = dpp_ror1(j2w);
    }

    // --- steps 1..31: pure VALU ---
    #pragma unroll 4
    for (int s = 1; s < 32; ++s) {
        #pragma unroll
        for (int k = 0; k < RPTS; ++k) {
            float t1 = fmaf(j1x, px[k], j1w);
            t1 = fmaf(j1y, py[k], t1);
            t1 = fmaf(j1z, pz[k], t1);
            float t2 = fmaf(j2x, px[k], j2w);
            t2 = fmaf(j2y, py[k], t2);
            t2 = fmaf(j2z, pz[k], t2);
            acc[k] = fminf(acc[k], fminf(t1, t2));   // -> v_min3_f32
        }
        j1x = dpp_ror1(j1x); j1y = dpp_ror1(j1y);
        j1z = dpp_ror1(j1z); j1w = dpp_ror1(j1w);
        j2x = dpp_ror1(j2x); j2y = dpp_ror1(j2y);
        j2z = dpp_ror1(j2z); j2w = dpp_ror1(j2w);
    }

    float* mb = part_mins + (((size_t)mode * NB + b) * NJC + jc) * NPTS;
    #pragma unroll
    for (int k = 0; k < RPTS; ++k)
        mb[(k << 8) + tid] = acc[k] + p2[k];         // coalesced per k
}

// ---------------------------------------------------------------------------
__device__ __forceinline__ float block_sum(float v, float* red)
{
    #pragma unroll
    for (int o = 32; o >= 1; o >>= 1) v += __shfl_xor(v, o);
    const int w = threadIdx.x >> 6;
    __syncthreads();
    if ((threadIdx.x & 63) == 0) red[w] = v;
    __syncthreads();
    return red[0] + red[1] + red[2] + red[3];
}

// ---------------------------------------------------------------------------
// Fold: blocks 0..191 fold NJC partials per 256-i slice -> sum & sumsq
// (blk = mode*64 + b*16 + slice). Block 192: KL. Block 193: sizing.
// ---------------------------------------------------------------------------
__global__ __launch_bounds__(256) void k_fold(
    const float* __restrict__ part_mins,
    const float* __restrict__ pred_sizing,
    const float* __restrict__ targ_sizing,
    const float* __restrict__ mu,
    const float* __restrict__ logvar,
    float* __restrict__ sums /* [194] */,
    float* __restrict__ sumsqs /* [194] */)
{
    __shared__ float red[4];
    const int blk = blockIdx.x, tid = threadIdx.x;

    if (blk < 192) {
        const int slice = blk & 15;
        const int b     = (blk >> 4) & 3;
        const int mode  = blk >> 6;
        const float* base = part_mins + ((size_t)mode * NB + b) * NJC * NPTS
                            + slice * 256 + tid;
        float m = FLT_MAX;
        #pragma unroll 8
        for (int jc = 0; jc < NJC; ++jc)
            m = fminf(m, base[(size_t)jc * NPTS]);
        const float s  = block_sum(m, red);
        const float s2 = block_sum(m * m, red);
        if (tid == 0) { sums[blk] = s; sumsqs[blk] = s2; }
    } else if (blk == 192) {
        float kls = 0.f;
        for (int i = tid; i < NB * NLAT; i += 256) {
            const float lv = logvar[i], m = mu[i];
            kls += 1.f + lv - m * m - expf(lv);
        }
        kls = block_sum(kls, red);
        if (tid == 0) { sums[192] = kls; sumsqs[192] = 0.f; }
    } else {
        const float4* ps = (const float4*)pred_sizing;
        const float4* ts = (const float4*)targ_sizing;
        float szs = 0.f;
        #pragma unroll 4
        for (int i = tid; i < NB * NPTS / 4; i += 256) {
            const float4 a = ps[i], c = ts[i];
            const float d0 = a.x - c.x, d1 = a.y - c.y;
            const float d2 = a.z - c.z, d3 = a.w - c.w;
            szs += fmaf(d0, d0, fmaf(d1, d1, fmaf(d2, d2, d3 * d3)));
        }
        szs = block_sum(szs, red);
        if (tid == 0) { sums[193] = szs; sumsqs[193] = 0.f; }
    }
}

// ---------------------------------------------------------------------------
// Finalize: combine 194 scalars. grid = 1, block = 256.
// ---------------------------------------------------------------------------
__global__ __launch_bounds__(256) void k_finalize(
    const float* __restrict__ sums, const float* __restrict__ sumsqs,
    float* __restrict__ out)
{
    __shared__ float gs[12], gq[12];
    const int t = threadIdx.x;

    float v = 0.f, v2 = 0.f;
    if (t < 192) { v = sums[t]; v2 = sumsqs[t]; }
    #pragma unroll
    for (int o = 1; o < 16; o <<= 1) {
        v  += __shfl_xor(v,  o);
        v2 += __shfl_xor(v2, o);
    }
    if (t < 192 && (t & 15) == 0) { gs[t >> 4] = v; gq[t >> 4] = v2; }
    __syncthreads();

    if (t == 0) {
        float cd = 0.f, dens = 0.f;
        for (int b = 0; b < NB; ++b) {
            const float s01 = gs[b] + gs[4 + b];
            const float sS  = gs[8 + b];
            const float sS2 = gq[8 + b];
            cd += s01 / (float)NPTS;
            const float var = (sS2 - sS * sS / (float)NPTS) / (float)(NPTS - 1);
            dens += sqrtf(fmaxf(var, 0.f));
        }
        cd   /= (float)NB;
        dens /= (float)NB;
        const float kl     = -0.5f * sums[192] / (float)(NB * NLAT);
        const float sizing = sums[193] / (float)(NB * NPTS);
        out[0] = cd + 0.001f * kl + 0.1f * dens + 0.05f * sizing;
    }
}

// ---------------------------------------------------------------------------
extern "C" void kernel_launch(void* const* d_in, const int* in_sizes, int n_in,
                              void* d_out, int out_size, void* d_ws, size_t ws_size,
                              hipStream_t stream)
{
    const float* pred_pos    = (const float*)d_in[0];
    const float* pred_sizing = (const float*)d_in[1];
    const float* targ_pos    = (const float*)d_in[2];
    const float* targ_sizing = (const float*)d_in[3];
    const float* mu          = (const float*)d_in[4];
    const float* logvar      = (const float*)d_in[5];

    float4* predT = (float4*)d_ws;                               // 256 KiB
    float4* predR = predT + (size_t)NB * NPTS;
    float4* targT = predR + (size_t)NB * NPTS;
    float4* targR = targT + (size_t)NB * NPTS;
    float*  part_mins = (float*)(targR + (size_t)NB * NPTS);     // 12.6 MiB
    float*  sums   = part_mins + (size_t)3 * NB * NJC * NPTS;    // 194
    float*  sumsqs = sums + 194;                                 // 194

    k_prep<<<dim3(NB * NPTS / 256), dim3(256), 0, stream>>>(
        pred_pos, targ_pos, predT, predR, targT, targR);
    k_min_dist<<<dim3(3 * NB * NJC), dim3(256), 0, stream>>>(
        predT, predR, targT, targR, part_mins);
    k_fold<<<dim3(194), dim3(256), 0, stream>>>(
        part_mins, pred_sizing, targ_sizing, mu, logvar, sums, sumsqs);
    k_finalize<<<dim3(1), dim3(256), 0, stream>>>(sums, sumsqs, (float*)d_out);
}